// Round 1
// baseline (33.533 us; speedup 1.0000x reference)
//
#include <hip/hip_runtime.h>
#include <math.h>

#ifndef M_PI
#define M_PI 3.14159265358979323846
#endif

#define MA 768  // MAX_ATOMS

__device__ __forceinline__ float wred64(float v) {
#pragma unroll
    for (int off = 32; off; off >>= 1) v += __shfl_xor(v, off, 64);
    return v;
}

__global__ __launch_bounds__(64) void kabsch_rmsd_kernel(
    const float* __restrict__ inp, const float* __restrict__ tgt,
    const int* __restrict__ natoms, float* __restrict__ out)
{
    const int b = blockIdx.x;
    const int lane = threadIdx.x;
    const int n = natoms[b];
    const float* __restrict__ X = inp + (size_t)b * (3 * MA);
    const float* __restrict__ Y = tgt + (size_t)b * (3 * MA);

    // one-pass accumulators (17 scalars)
    float sx0 = 0.f, sx1 = 0.f, sx2 = 0.f;
    float sy0 = 0.f, sy1 = 0.f, sy2 = 0.f;
    float c00 = 0.f, c01 = 0.f, c02 = 0.f;
    float c10 = 0.f, c11 = 0.f, c12 = 0.f;
    float c20 = 0.f, c21 = 0.f, c22 = 0.f;
    float nx2 = 0.f, ny2 = 0.f;

#pragma unroll
    for (int a0 = 0; a0 < MA; a0 += 64) {
        int a = a0 + lane;
        if (a < n) {
            float x0 = X[3 * a + 0], x1 = X[3 * a + 1], x2 = X[3 * a + 2];
            float y0 = Y[3 * a + 0], y1 = Y[3 * a + 1], y2 = Y[3 * a + 2];
            sx0 += x0; sx1 += x1; sx2 += x2;
            sy0 += y0; sy1 += y1; sy2 += y2;
            c00 = fmaf(x0, y0, c00); c01 = fmaf(x0, y1, c01); c02 = fmaf(x0, y2, c02);
            c10 = fmaf(x1, y0, c10); c11 = fmaf(x1, y1, c11); c12 = fmaf(x1, y2, c12);
            c20 = fmaf(x2, y0, c20); c21 = fmaf(x2, y1, c21); c22 = fmaf(x2, y2, c22);
            nx2 = fmaf(x0, x0, nx2); nx2 = fmaf(x1, x1, nx2); nx2 = fmaf(x2, x2, nx2);
            ny2 = fmaf(y0, y0, ny2); ny2 = fmaf(y1, y1, ny2); ny2 = fmaf(y2, y2, ny2);
        }
    }

    // 64-lane tree reduce of all 17 accumulators
    sx0 = wred64(sx0); sx1 = wred64(sx1); sx2 = wred64(sx2);
    sy0 = wred64(sy0); sy1 = wred64(sy1); sy2 = wred64(sy2);
    c00 = wred64(c00); c01 = wred64(c01); c02 = wred64(c02);
    c10 = wred64(c10); c11 = wred64(c11); c12 = wred64(c12);
    c20 = wred64(c20); c21 = wred64(c21); c22 = wred64(c22);
    nx2 = wred64(nx2); ny2 = wred64(ny2);

    if (lane == 0) {
        const double dn = (double)n;

        // centered correlation matrix R = Xc^T Yc and centered norms
        double R00 = (double)c00 - (double)sx0 * (double)sy0 / dn;
        double R01 = (double)c01 - (double)sx0 * (double)sy1 / dn;
        double R02 = (double)c02 - (double)sx0 * (double)sy2 / dn;
        double R10 = (double)c10 - (double)sx1 * (double)sy0 / dn;
        double R11 = (double)c11 - (double)sx1 * (double)sy1 / dn;
        double R12 = (double)c12 - (double)sx1 * (double)sy2 / dn;
        double R20 = (double)c20 - (double)sx2 * (double)sy0 / dn;
        double R21 = (double)c21 - (double)sx2 * (double)sy1 / dn;
        double R22 = (double)c22 - (double)sx2 * (double)sy2 / dn;
        double ex = (double)nx2 -
            ((double)sx0 * sx0 + (double)sx1 * sx1 + (double)sx2 * sx2) / dn;
        double ey = (double)ny2 -
            ((double)sy0 * sy0 + (double)sy1 * sy1 + (double)sy2 * sy2) / dn;

        // A = R^T R (symmetric, PSD); its eigenvalues are squared singular values
        double A00 = R00 * R00 + R10 * R10 + R20 * R20;
        double A11 = R01 * R01 + R11 * R11 + R21 * R21;
        double A22 = R02 * R02 + R12 * R12 + R22 * R22;
        double A01 = R00 * R01 + R10 * R11 + R20 * R21;
        double A02 = R00 * R02 + R10 * R12 + R20 * R22;
        double A12 = R01 * R02 + R11 * R12 + R21 * R22;

        double detR = R00 * (R11 * R22 - R12 * R21)
                    - R01 * (R10 * R22 - R12 * R20)
                    + R02 * (R10 * R21 - R11 * R20);

        // closed-form symmetric 3x3 eigenvalues (Cardano / trigonometric)
        double q = (A00 + A11 + A22) / 3.0;
        double p1 = A01 * A01 + A02 * A02 + A12 * A12;
        double b00 = A00 - q, b11 = A11 - q, b22 = A22 - q;
        double p2 = b00 * b00 + b11 * b11 + b22 * b22 + 2.0 * p1;
        double e0, e1, e2;
        if (p2 <= 0.0) {
            e0 = e1 = e2 = q;
        } else {
            double p = sqrt(p2 / 6.0);
            double ip = 1.0 / p;
            double B00 = b00 * ip, B11 = b11 * ip, B22 = b22 * ip;
            double B01 = A01 * ip, B02 = A02 * ip, B12 = A12 * ip;
            double detB = B00 * (B11 * B22 - B12 * B12)
                        - B01 * (B01 * B22 - B12 * B02)
                        + B02 * (B01 * B12 - B11 * B02);
            double r = 0.5 * detB;
            r = fmin(1.0, fmax(-1.0, r));
            double phi = acos(r) / 3.0;
            e0 = q + 2.0 * p * cos(phi);                    // largest
            e2 = q + 2.0 * p * cos(phi + 2.0 * M_PI / 3.0); // smallest
            e1 = 3.0 * q - e0 - e2;
        }
        double s0 = sqrt(fmax(e0, 0.0));
        double s1 = sqrt(fmax(e1, 0.0));
        double s2 = sqrt(fmax(e2, 0.0));
        double d = (detR > 0.0) ? 1.0 : ((detR < 0.0) ? -1.0 : 0.0);
        double tr = s0 + s1 + d * s2;
        double e = ex + ey - 2.0 * tr;
        out[b] = (float)sqrt(fmax(e, 0.0) / dn + 1e-7);
    }
}

extern "C" void kernel_launch(void* const* d_in, const int* in_sizes, int n_in,
                              void* d_out, int out_size, void* d_ws, size_t ws_size,
                              hipStream_t stream) {
    const float* inp = (const float*)d_in[0];
    const float* tgt = (const float*)d_in[1];
    const int* natoms = (const int*)d_in[2];
    float* out = (float*)d_out;
    (void)d_ws; (void)ws_size; (void)n_in; (void)in_sizes;
    kabsch_rmsd_kernel<<<dim3(out_size), dim3(64), 0, stream>>>(inp, tgt, natoms, out);
}

// Round 2
// 29.716 us; speedup vs baseline: 1.1285x; 1.1285x over previous
//
#include <hip/hip_runtime.h>
#include <math.h>

#ifndef M_PI
#define M_PI 3.14159265358979323846
#endif

#define MA 768  // MAX_ATOMS

__device__ __forceinline__ float wred64(float v) {
#pragma unroll
    for (int off = 32; off; off >>= 1) v += __shfl_xor(v, off, 64);
    return v;
}

__global__ __launch_bounds__(256) void kabsch_rmsd_kernel(
    const float* __restrict__ inp, const float* __restrict__ tgt,
    const int* __restrict__ natoms, float* __restrict__ out)
{
    const int wave = threadIdx.x >> 6;
    const int lane = threadIdx.x & 63;
    const int b = blockIdx.x * 4 + wave;
    const int n = natoms[b];
    const float* __restrict__ X = inp + (size_t)b * (3 * MA);
    const float* __restrict__ Y = tgt + (size_t)b * (3 * MA);

    // one-pass accumulators (17 scalars)
    float sx0 = 0.f, sx1 = 0.f, sx2 = 0.f;
    float sy0 = 0.f, sy1 = 0.f, sy2 = 0.f;
    float c00 = 0.f, c01 = 0.f, c02 = 0.f;
    float c10 = 0.f, c11 = 0.f, c12 = 0.f;
    float c20 = 0.f, c21 = 0.f, c22 = 0.f;
    float nx2 = 0.f, ny2 = 0.f;

    auto acc = [&](float x0, float x1, float x2, float y0, float y1, float y2) {
        sx0 += x0; sx1 += x1; sx2 += x2;
        sy0 += y0; sy1 += y1; sy2 += y2;
        c00 = fmaf(x0, y0, c00); c01 = fmaf(x0, y1, c01); c02 = fmaf(x0, y2, c02);
        c10 = fmaf(x1, y0, c10); c11 = fmaf(x1, y1, c11); c12 = fmaf(x1, y2, c12);
        c20 = fmaf(x2, y0, c20); c21 = fmaf(x2, y1, c21); c22 = fmaf(x2, y2, c22);
        nx2 = fmaf(x0, x0, nx2); nx2 = fmaf(x1, x1, nx2); nx2 = fmaf(x2, x2, nx2);
        ny2 = fmaf(y0, y0, ny2); ny2 = fmaf(y1, y1, ny2); ny2 = fmaf(y2, y2, ny2);
    };

    // each lane handles 4 whole atoms per iteration: 3x float4 = 12 floats, contiguous
#pragma unroll
    for (int it = 0; it < 3; ++it) {
        const int base = it * 256 + lane * 4;  // first atom of this lane's group
        if (base < n) {
            const float4* px = (const float4*)(X + 3 * base);
            const float4* py = (const float4*)(Y + 3 * base);
            float4 fx0 = px[0], fx1 = px[1], fx2 = px[2];
            float4 fy0 = py[0], fy1 = py[1], fy2 = py[2];

            // atom 0: always valid here (base < n)
            acc(fx0.x, fx0.y, fx0.z, fy0.x, fy0.y, fy0.z);
            // atom 1
            {
                bool v = (base + 1) < n;
                float x0 = v ? fx0.w : 0.f, x1 = v ? fx1.x : 0.f, x2 = v ? fx1.y : 0.f;
                float y0 = v ? fy0.w : 0.f, y1 = v ? fy1.x : 0.f, y2 = v ? fy1.y : 0.f;
                acc(x0, x1, x2, y0, y1, y2);
            }
            // atom 2
            {
                bool v = (base + 2) < n;
                float x0 = v ? fx1.z : 0.f, x1 = v ? fx1.w : 0.f, x2 = v ? fx2.x : 0.f;
                float y0 = v ? fy1.z : 0.f, y1 = v ? fy1.w : 0.f, y2 = v ? fy2.x : 0.f;
                acc(x0, x1, x2, y0, y1, y2);
            }
            // atom 3
            {
                bool v = (base + 3) < n;
                float x0 = v ? fx2.y : 0.f, x1 = v ? fx2.z : 0.f, x2 = v ? fx2.w : 0.f;
                float y0 = v ? fy2.y : 0.f, y1 = v ? fy2.z : 0.f, y2 = v ? fy2.w : 0.f;
                acc(x0, x1, x2, y0, y1, y2);
            }
        }
    }

    // 64-lane tree reduce of all 17 accumulators
    sx0 = wred64(sx0); sx1 = wred64(sx1); sx2 = wred64(sx2);
    sy0 = wred64(sy0); sy1 = wred64(sy1); sy2 = wred64(sy2);
    c00 = wred64(c00); c01 = wred64(c01); c02 = wred64(c02);
    c10 = wred64(c10); c11 = wred64(c11); c12 = wred64(c12);
    c20 = wred64(c20); c21 = wred64(c21); c22 = wred64(c22);
    nx2 = wred64(nx2); ny2 = wred64(ny2);

    if (lane == 0) {
        const double dn = (double)n;

        // centered correlation matrix R = Xc^T Yc and centered norms
        double R00 = (double)c00 - (double)sx0 * (double)sy0 / dn;
        double R01 = (double)c01 - (double)sx0 * (double)sy1 / dn;
        double R02 = (double)c02 - (double)sx0 * (double)sy2 / dn;
        double R10 = (double)c10 - (double)sx1 * (double)sy0 / dn;
        double R11 = (double)c11 - (double)sx1 * (double)sy1 / dn;
        double R12 = (double)c12 - (double)sx1 * (double)sy2 / dn;
        double R20 = (double)c20 - (double)sx2 * (double)sy0 / dn;
        double R21 = (double)c21 - (double)sx2 * (double)sy1 / dn;
        double R22 = (double)c22 - (double)sx2 * (double)sy2 / dn;
        double ex = (double)nx2 -
            ((double)sx0 * sx0 + (double)sx1 * sx1 + (double)sx2 * sx2) / dn;
        double ey = (double)ny2 -
            ((double)sy0 * sy0 + (double)sy1 * sy1 + (double)sy2 * sy2) / dn;

        // A = R^T R (symmetric, PSD); eigenvalues are squared singular values
        double A00 = R00 * R00 + R10 * R10 + R20 * R20;
        double A11 = R01 * R01 + R11 * R11 + R21 * R21;
        double A22 = R02 * R02 + R12 * R12 + R22 * R22;
        double A01 = R00 * R01 + R10 * R11 + R20 * R21;
        double A02 = R00 * R02 + R10 * R12 + R20 * R22;
        double A12 = R01 * R02 + R11 * R12 + R21 * R22;

        double detR = R00 * (R11 * R22 - R12 * R21)
                    - R01 * (R10 * R22 - R12 * R20)
                    + R02 * (R10 * R21 - R11 * R20);

        // closed-form symmetric 3x3 eigenvalues (Cardano / trigonometric)
        double q = (A00 + A11 + A22) / 3.0;
        double p1 = A01 * A01 + A02 * A02 + A12 * A12;
        double b00 = A00 - q, b11 = A11 - q, b22 = A22 - q;
        double p2 = b00 * b00 + b11 * b11 + b22 * b22 + 2.0 * p1;
        double e0, e1, e2;
        if (p2 <= 0.0) {
            e0 = e1 = e2 = q;
        } else {
            double p = sqrt(p2 / 6.0);
            double ip = 1.0 / p;
            double B00 = b00 * ip, B11 = b11 * ip, B22 = b22 * ip;
            double B01 = A01 * ip, B02 = A02 * ip, B12 = A12 * ip;
            double detB = B00 * (B11 * B22 - B12 * B12)
                        - B01 * (B01 * B22 - B12 * B02)
                        + B02 * (B01 * B12 - B11 * B02);
            double r = 0.5 * detB;
            r = fmin(1.0, fmax(-1.0, r));
            double phi = acos(r) / 3.0;
            e0 = q + 2.0 * p * cos(phi);                    // largest
            e2 = q + 2.0 * p * cos(phi + 2.0 * M_PI / 3.0); // smallest
            e1 = 3.0 * q - e0 - e2;
        }
        double s0 = sqrt(fmax(e0, 0.0));
        double s1 = sqrt(fmax(e1, 0.0));
        double s2 = sqrt(fmax(e2, 0.0));
        double d = (detR > 0.0) ? 1.0 : ((detR < 0.0) ? -1.0 : 0.0);
        double tr = s0 + s1 + d * s2;
        double e = ex + ey - 2.0 * tr;
        out[b] = (float)sqrt(fmax(e, 0.0) / dn + 1e-7);
    }
}

extern "C" void kernel_launch(void* const* d_in, const int* in_sizes, int n_in,
                              void* d_out, int out_size, void* d_ws, size_t ws_size,
                              hipStream_t stream) {
    const float* inp = (const float*)d_in[0];
    const float* tgt = (const float*)d_in[1];
    const int* natoms = (const int*)d_in[2];
    float* out = (float*)d_out;
    (void)d_ws; (void)ws_size; (void)n_in; (void)in_sizes;
    kabsch_rmsd_kernel<<<dim3(out_size / 4), dim3(256), 0, stream>>>(inp, tgt, natoms, out);
}

// Round 3
// 28.088 us; speedup vs baseline: 1.1938x; 1.0579x over previous
//
#include <hip/hip_runtime.h>
#include <math.h>

#ifndef M_PI
#define M_PI 3.14159265358979323846
#endif

#define MA 768   // MAX_ATOMS
#define NB 8192  // batch

// Full-wave (64-lane) sum via DPP on the VALU pipe (no DS traffic).
// rocPRIM sequence; the total lands in lane 63.
__device__ __forceinline__ float dpp_red_add(float v) {
    v += __int_as_float(__builtin_amdgcn_update_dpp(0, __float_as_int(v), 0x111, 0xf, 0xf, true)); // row_shr:1
    v += __int_as_float(__builtin_amdgcn_update_dpp(0, __float_as_int(v), 0x112, 0xf, 0xf, true)); // row_shr:2
    v += __int_as_float(__builtin_amdgcn_update_dpp(0, __float_as_int(v), 0x114, 0xf, 0xe, true)); // row_shr:4
    v += __int_as_float(__builtin_amdgcn_update_dpp(0, __float_as_int(v), 0x118, 0xf, 0xc, true)); // row_shr:8
    v += __int_as_float(__builtin_amdgcn_update_dpp(0, __float_as_int(v), 0x142, 0xa, 0xf, true)); // row_bcast:15
    v += __int_as_float(__builtin_amdgcn_update_dpp(0, __float_as_int(v), 0x143, 0xc, 0xf, true)); // row_bcast:31
    return v;
}

// Kernel A: per-sample one-pass reduction to 17 scalars, written to ws (SoA).
__global__ __launch_bounds__(256) void kabsch_reduce_kernel(
    const float* __restrict__ inp, const float* __restrict__ tgt,
    const int* __restrict__ natoms, float* __restrict__ ws)
{
    const int wave = threadIdx.x >> 6;
    const int lane = threadIdx.x & 63;
    const int b = blockIdx.x * 4 + wave;
    const int n = natoms[b];
    const float* __restrict__ X = inp + (size_t)b * (3 * MA);
    const float* __restrict__ Y = tgt + (size_t)b * (3 * MA);

    float sx0 = 0.f, sx1 = 0.f, sx2 = 0.f;
    float sy0 = 0.f, sy1 = 0.f, sy2 = 0.f;
    float c00 = 0.f, c01 = 0.f, c02 = 0.f;
    float c10 = 0.f, c11 = 0.f, c12 = 0.f;
    float c20 = 0.f, c21 = 0.f, c22 = 0.f;
    float nx2 = 0.f, ny2 = 0.f;

    auto acc = [&](float x0, float x1, float x2, float y0, float y1, float y2) {
        sx0 += x0; sx1 += x1; sx2 += x2;
        sy0 += y0; sy1 += y1; sy2 += y2;
        c00 = fmaf(x0, y0, c00); c01 = fmaf(x0, y1, c01); c02 = fmaf(x0, y2, c02);
        c10 = fmaf(x1, y0, c10); c11 = fmaf(x1, y1, c11); c12 = fmaf(x1, y2, c12);
        c20 = fmaf(x2, y0, c20); c21 = fmaf(x2, y1, c21); c22 = fmaf(x2, y2, c22);
        nx2 = fmaf(x0, x0, nx2); nx2 = fmaf(x1, x1, nx2); nx2 = fmaf(x2, x2, nx2);
        ny2 = fmaf(y0, y0, ny2); ny2 = fmaf(y1, y1, ny2); ny2 = fmaf(y2, y2, ny2);
    };

    // each lane handles 4 whole atoms per iteration: 3x float4 = 12 floats, contiguous
#pragma unroll
    for (int it = 0; it < 3; ++it) {
        const int base = it * 256 + lane * 4;
        if (base < n) {
            const float4* px = (const float4*)(X + 3 * base);
            const float4* py = (const float4*)(Y + 3 * base);
            float4 fx0 = px[0], fx1 = px[1], fx2 = px[2];
            float4 fy0 = py[0], fy1 = py[1], fy2 = py[2];

            acc(fx0.x, fx0.y, fx0.z, fy0.x, fy0.y, fy0.z);
            {
                bool v = (base + 1) < n;
                acc(v ? fx0.w : 0.f, v ? fx1.x : 0.f, v ? fx1.y : 0.f,
                    v ? fy0.w : 0.f, v ? fy1.x : 0.f, v ? fy1.y : 0.f);
            }
            {
                bool v = (base + 2) < n;
                acc(v ? fx1.z : 0.f, v ? fx1.w : 0.f, v ? fx2.x : 0.f,
                    v ? fy1.z : 0.f, v ? fy1.w : 0.f, v ? fy2.x : 0.f);
            }
            {
                bool v = (base + 3) < n;
                acc(v ? fx2.y : 0.f, v ? fx2.z : 0.f, v ? fx2.w : 0.f,
                    v ? fy2.y : 0.f, v ? fy2.z : 0.f, v ? fy2.w : 0.f);
            }
        }
    }

    sx0 = dpp_red_add(sx0); sx1 = dpp_red_add(sx1); sx2 = dpp_red_add(sx2);
    sy0 = dpp_red_add(sy0); sy1 = dpp_red_add(sy1); sy2 = dpp_red_add(sy2);
    c00 = dpp_red_add(c00); c01 = dpp_red_add(c01); c02 = dpp_red_add(c02);
    c10 = dpp_red_add(c10); c11 = dpp_red_add(c11); c12 = dpp_red_add(c12);
    c20 = dpp_red_add(c20); c21 = dpp_red_add(c21); c22 = dpp_red_add(c22);
    nx2 = dpp_red_add(nx2); ny2 = dpp_red_add(ny2);

    if (lane == 63) {
        ws[ 0 * NB + b] = sx0; ws[ 1 * NB + b] = sx1; ws[ 2 * NB + b] = sx2;
        ws[ 3 * NB + b] = sy0; ws[ 4 * NB + b] = sy1; ws[ 5 * NB + b] = sy2;
        ws[ 6 * NB + b] = c00; ws[ 7 * NB + b] = c01; ws[ 8 * NB + b] = c02;
        ws[ 9 * NB + b] = c10; ws[10 * NB + b] = c11; ws[11 * NB + b] = c12;
        ws[12 * NB + b] = c20; ws[13 * NB + b] = c21; ws[14 * NB + b] = c22;
        ws[15 * NB + b] = nx2; ws[16 * NB + b] = ny2;
    }
}

// Kernel B: one thread per sample — centered R, 3x3 eigensolve, RMSD.
__global__ __launch_bounds__(256) void kabsch_finish_kernel(
    const float* __restrict__ ws, const int* __restrict__ natoms,
    float* __restrict__ out)
{
    const int b = blockIdx.x * 256 + threadIdx.x;
    const int n = natoms[b];
    const double dn = (double)n;

    const float sx0 = ws[ 0 * NB + b], sx1 = ws[ 1 * NB + b], sx2 = ws[ 2 * NB + b];
    const float sy0 = ws[ 3 * NB + b], sy1 = ws[ 4 * NB + b], sy2 = ws[ 5 * NB + b];
    const float c00 = ws[ 6 * NB + b], c01 = ws[ 7 * NB + b], c02 = ws[ 8 * NB + b];
    const float c10 = ws[ 9 * NB + b], c11 = ws[10 * NB + b], c12 = ws[11 * NB + b];
    const float c20 = ws[12 * NB + b], c21 = ws[13 * NB + b], c22 = ws[14 * NB + b];
    const float nx2 = ws[15 * NB + b], ny2 = ws[16 * NB + b];

    double R00 = (double)c00 - (double)sx0 * (double)sy0 / dn;
    double R01 = (double)c01 - (double)sx0 * (double)sy1 / dn;
    double R02 = (double)c02 - (double)sx0 * (double)sy2 / dn;
    double R10 = (double)c10 - (double)sx1 * (double)sy0 / dn;
    double R11 = (double)c11 - (double)sx1 * (double)sy1 / dn;
    double R12 = (double)c12 - (double)sx1 * (double)sy2 / dn;
    double R20 = (double)c20 - (double)sx2 * (double)sy0 / dn;
    double R21 = (double)c21 - (double)sx2 * (double)sy1 / dn;
    double R22 = (double)c22 - (double)sx2 * (double)sy2 / dn;
    double ex = (double)nx2 -
        ((double)sx0 * sx0 + (double)sx1 * sx1 + (double)sx2 * sx2) / dn;
    double ey = (double)ny2 -
        ((double)sy0 * sy0 + (double)sy1 * sy1 + (double)sy2 * sy2) / dn;

    // A = R^T R (symmetric PSD); eigenvalues are squared singular values
    double A00 = R00 * R00 + R10 * R10 + R20 * R20;
    double A11 = R01 * R01 + R11 * R11 + R21 * R21;
    double A22 = R02 * R02 + R12 * R12 + R22 * R22;
    double A01 = R00 * R01 + R10 * R11 + R20 * R21;
    double A02 = R00 * R02 + R10 * R12 + R20 * R22;
    double A12 = R01 * R02 + R11 * R12 + R21 * R22;

    double detR = R00 * (R11 * R22 - R12 * R21)
                - R01 * (R10 * R22 - R12 * R20)
                + R02 * (R10 * R21 - R11 * R20);

    double q = (A00 + A11 + A22) / 3.0;
    double p1 = A01 * A01 + A02 * A02 + A12 * A12;
    double b00 = A00 - q, b11 = A11 - q, b22 = A22 - q;
    double p2 = b00 * b00 + b11 * b11 + b22 * b22 + 2.0 * p1;
    double e0, e1, e2;
    if (p2 <= 0.0) {
        e0 = e1 = e2 = q;
    } else {
        double p = sqrt(p2 / 6.0);
        double ip = 1.0 / p;
        double B00 = b00 * ip, B11 = b11 * ip, B22 = b22 * ip;
        double B01 = A01 * ip, B02 = A02 * ip, B12 = A12 * ip;
        double detB = B00 * (B11 * B22 - B12 * B12)
                    - B01 * (B01 * B22 - B12 * B02)
                    + B02 * (B01 * B12 - B11 * B02);
        double r = 0.5 * detB;
        r = fmin(1.0, fmax(-1.0, r));
        double phi = acos(r) / 3.0;
        e0 = q + 2.0 * p * cos(phi);
        e2 = q + 2.0 * p * cos(phi + 2.0 * M_PI / 3.0);
        e1 = 3.0 * q - e0 - e2;
    }
    double s0 = sqrt(fmax(e0, 0.0));
    double s1 = sqrt(fmax(e1, 0.0));
    double s2 = sqrt(fmax(e2, 0.0));
    double d = (detR > 0.0) ? 1.0 : ((detR < 0.0) ? -1.0 : 0.0);
    double tr = s0 + s1 + d * s2;
    double e = ex + ey - 2.0 * tr;
    out[b] = (float)sqrt(fmax(e, 0.0) / dn + 1e-7);
}

extern "C" void kernel_launch(void* const* d_in, const int* in_sizes, int n_in,
                              void* d_out, int out_size, void* d_ws, size_t ws_size,
                              hipStream_t stream) {
    const float* inp = (const float*)d_in[0];
    const float* tgt = (const float*)d_in[1];
    const int* natoms = (const int*)d_in[2];
    float* out = (float*)d_out;
    float* ws = (float*)d_ws;
    (void)ws_size; (void)n_in; (void)in_sizes;
    kabsch_reduce_kernel<<<dim3(out_size / 4), dim3(256), 0, stream>>>(inp, tgt, natoms, ws);
    kabsch_finish_kernel<<<dim3(out_size / 256), dim3(256), 0, stream>>>(ws, natoms, out);
}

// Round 4
// 27.591 us; speedup vs baseline: 1.2154x; 1.0180x over previous
//
#include <hip/hip_runtime.h>
#include <math.h>

#ifndef M_PI
#define M_PI 3.14159265358979323846
#endif

#define MA 768   // MAX_ATOMS
#define NB 8192  // batch

// Full-wave (64-lane) sum via DPP on the VALU pipe (no DS traffic).
// rocPRIM sequence; the total lands in lane 63.
__device__ __forceinline__ float dpp_red_add(float v) {
    v += __int_as_float(__builtin_amdgcn_update_dpp(0, __float_as_int(v), 0x111, 0xf, 0xf, true)); // row_shr:1
    v += __int_as_float(__builtin_amdgcn_update_dpp(0, __float_as_int(v), 0x112, 0xf, 0xf, true)); // row_shr:2
    v += __int_as_float(__builtin_amdgcn_update_dpp(0, __float_as_int(v), 0x114, 0xf, 0xe, true)); // row_shr:4
    v += __int_as_float(__builtin_amdgcn_update_dpp(0, __float_as_int(v), 0x118, 0xf, 0xc, true)); // row_shr:8
    v += __int_as_float(__builtin_amdgcn_update_dpp(0, __float_as_int(v), 0x142, 0xa, 0xf, true)); // row_bcast:15
    v += __int_as_float(__builtin_amdgcn_update_dpp(0, __float_as_int(v), 0x143, 0xc, 0xf, true)); // row_bcast:31
    return v;
}

// Kernel A: one sample per 192-thread block; wave w owns atoms [w*256, w*256+256).
// Each lane: 4 atoms = 6 float4 loads issued together -> ONE memory round-trip.
__global__ __launch_bounds__(192) void kabsch_reduce_kernel(
    const float* __restrict__ inp, const float* __restrict__ tgt,
    const int* __restrict__ natoms, float* __restrict__ ws)
{
    const int wave = threadIdx.x >> 6;   // chunk id 0..2
    const int lane = threadIdx.x & 63;
    const int b = blockIdx.x;
    const int n = natoms[b];
    const float* __restrict__ X = inp + (size_t)b * (3 * MA);
    const float* __restrict__ Y = tgt + (size_t)b * (3 * MA);

    float sx0 = 0.f, sx1 = 0.f, sx2 = 0.f;
    float sy0 = 0.f, sy1 = 0.f, sy2 = 0.f;
    float c00 = 0.f, c01 = 0.f, c02 = 0.f;
    float c10 = 0.f, c11 = 0.f, c12 = 0.f;
    float c20 = 0.f, c21 = 0.f, c22 = 0.f;
    float nx2 = 0.f, ny2 = 0.f;

    auto acc = [&](float x0, float x1, float x2, float y0, float y1, float y2) {
        sx0 += x0; sx1 += x1; sx2 += x2;
        sy0 += y0; sy1 += y1; sy2 += y2;
        c00 = fmaf(x0, y0, c00); c01 = fmaf(x0, y1, c01); c02 = fmaf(x0, y2, c02);
        c10 = fmaf(x1, y0, c10); c11 = fmaf(x1, y1, c11); c12 = fmaf(x1, y2, c12);
        c20 = fmaf(x2, y0, c20); c21 = fmaf(x2, y1, c21); c22 = fmaf(x2, y2, c22);
        nx2 = fmaf(x0, x0, nx2); nx2 = fmaf(x1, x1, nx2); nx2 = fmaf(x2, x2, nx2);
        ny2 = fmaf(y0, y0, ny2); ny2 = fmaf(y1, y1, ny2); ny2 = fmaf(y2, y2, ny2);
    };

    const int base = wave * 256 + lane * 4;  // this lane's first atom
    if (base < n) {                          // whole wave skips if chunk beyond n
        const float4* px = (const float4*)(X + 3 * base);
        const float4* py = (const float4*)(Y + 3 * base);
        float4 fx0 = px[0], fx1 = px[1], fx2 = px[2];
        float4 fy0 = py[0], fy1 = py[1], fy2 = py[2];

        acc(fx0.x, fx0.y, fx0.z, fy0.x, fy0.y, fy0.z);  // atom 0 valid (base < n)
        {
            bool v = (base + 1) < n;
            acc(v ? fx0.w : 0.f, v ? fx1.x : 0.f, v ? fx1.y : 0.f,
                v ? fy0.w : 0.f, v ? fy1.x : 0.f, v ? fy1.y : 0.f);
        }
        {
            bool v = (base + 2) < n;
            acc(v ? fx1.z : 0.f, v ? fx1.w : 0.f, v ? fx2.x : 0.f,
                v ? fy1.z : 0.f, v ? fy1.w : 0.f, v ? fy2.x : 0.f);
        }
        {
            bool v = (base + 3) < n;
            acc(v ? fx2.y : 0.f, v ? fx2.z : 0.f, v ? fx2.w : 0.f,
                v ? fy2.y : 0.f, v ? fy2.z : 0.f, v ? fy2.w : 0.f);
        }
    }

    sx0 = dpp_red_add(sx0); sx1 = dpp_red_add(sx1); sx2 = dpp_red_add(sx2);
    sy0 = dpp_red_add(sy0); sy1 = dpp_red_add(sy1); sy2 = dpp_red_add(sy2);
    c00 = dpp_red_add(c00); c01 = dpp_red_add(c01); c02 = dpp_red_add(c02);
    c10 = dpp_red_add(c10); c11 = dpp_red_add(c11); c12 = dpp_red_add(c12);
    c20 = dpp_red_add(c20); c21 = dpp_red_add(c21); c22 = dpp_red_add(c22);
    nx2 = dpp_red_add(nx2); ny2 = dpp_red_add(ny2);

    __shared__ float part[3][17];
    if (lane == 63) {
        part[wave][ 0] = sx0; part[wave][ 1] = sx1; part[wave][ 2] = sx2;
        part[wave][ 3] = sy0; part[wave][ 4] = sy1; part[wave][ 5] = sy2;
        part[wave][ 6] = c00; part[wave][ 7] = c01; part[wave][ 8] = c02;
        part[wave][ 9] = c10; part[wave][10] = c11; part[wave][11] = c12;
        part[wave][12] = c20; part[wave][13] = c21; part[wave][14] = c22;
        part[wave][15] = nx2; part[wave][16] = ny2;
    }
    __syncthreads();
    if (threadIdx.x < 17) {
        const int i = threadIdx.x;
        ws[i * NB + b] = part[0][i] + part[1][i] + part[2][i];
    }
}

// Kernel B: one thread per sample — centered R, 3x3 eigensolve, RMSD.
__global__ __launch_bounds__(256) void kabsch_finish_kernel(
    const float* __restrict__ ws, const int* __restrict__ natoms,
    float* __restrict__ out)
{
    const int b = blockIdx.x * 256 + threadIdx.x;
    const int n = natoms[b];
    const double dn = (double)n;

    const float sx0 = ws[ 0 * NB + b], sx1 = ws[ 1 * NB + b], sx2 = ws[ 2 * NB + b];
    const float sy0 = ws[ 3 * NB + b], sy1 = ws[ 4 * NB + b], sy2 = ws[ 5 * NB + b];
    const float c00 = ws[ 6 * NB + b], c01 = ws[ 7 * NB + b], c02 = ws[ 8 * NB + b];
    const float c10 = ws[ 9 * NB + b], c11 = ws[10 * NB + b], c12 = ws[11 * NB + b];
    const float c20 = ws[12 * NB + b], c21 = ws[13 * NB + b], c22 = ws[14 * NB + b];
    const float nx2 = ws[15 * NB + b], ny2 = ws[16 * NB + b];

    double R00 = (double)c00 - (double)sx0 * (double)sy0 / dn;
    double R01 = (double)c01 - (double)sx0 * (double)sy1 / dn;
    double R02 = (double)c02 - (double)sx0 * (double)sy2 / dn;
    double R10 = (double)c10 - (double)sx1 * (double)sy0 / dn;
    double R11 = (double)c11 - (double)sx1 * (double)sy1 / dn;
    double R12 = (double)c12 - (double)sx1 * (double)sy2 / dn;
    double R20 = (double)c20 - (double)sx2 * (double)sy0 / dn;
    double R21 = (double)c21 - (double)sx2 * (double)sy1 / dn;
    double R22 = (double)c22 - (double)sx2 * (double)sy2 / dn;
    double ex = (double)nx2 -
        ((double)sx0 * sx0 + (double)sx1 * sx1 + (double)sx2 * sx2) / dn;
    double ey = (double)ny2 -
        ((double)sy0 * sy0 + (double)sy1 * sy1 + (double)sy2 * sy2) / dn;

    // A = R^T R (symmetric PSD); eigenvalues are squared singular values
    double A00 = R00 * R00 + R10 * R10 + R20 * R20;
    double A11 = R01 * R01 + R11 * R11 + R21 * R21;
    double A22 = R02 * R02 + R12 * R12 + R22 * R22;
    double A01 = R00 * R01 + R10 * R11 + R20 * R21;
    double A02 = R00 * R02 + R10 * R12 + R20 * R22;
    double A12 = R01 * R02 + R11 * R12 + R21 * R22;

    double detR = R00 * (R11 * R22 - R12 * R21)
                - R01 * (R10 * R22 - R12 * R20)
                + R02 * (R10 * R21 - R11 * R20);

    double q = (A00 + A11 + A22) / 3.0;
    double p1 = A01 * A01 + A02 * A02 + A12 * A12;
    double b00 = A00 - q, b11 = A11 - q, b22 = A22 - q;
    double p2 = b00 * b00 + b11 * b11 + b22 * b22 + 2.0 * p1;
    double e0, e1, e2;
    if (p2 <= 0.0) {
        e0 = e1 = e2 = q;
    } else {
        double p = sqrt(p2 / 6.0);
        double ip = 1.0 / p;
        double B00 = b00 * ip, B11 = b11 * ip, B22 = b22 * ip;
        double B01 = A01 * ip, B02 = A02 * ip, B12 = A12 * ip;
        double detB = B00 * (B11 * B22 - B12 * B12)
                    - B01 * (B01 * B22 - B12 * B02)
                    + B02 * (B01 * B12 - B11 * B02);
        double r = 0.5 * detB;
        r = fmin(1.0, fmax(-1.0, r));
        double phi = acos(r) / 3.0;
        e0 = q + 2.0 * p * cos(phi);
        e2 = q + 2.0 * p * cos(phi + 2.0 * M_PI / 3.0);
        e1 = 3.0 * q - e0 - e2;
    }
    double s0 = sqrt(fmax(e0, 0.0));
    double s1 = sqrt(fmax(e1, 0.0));
    double s2 = sqrt(fmax(e2, 0.0));
    double d = (detR > 0.0) ? 1.0 : ((detR < 0.0) ? -1.0 : 0.0);
    double tr = s0 + s1 + d * s2;
    double e = ex + ey - 2.0 * tr;
    out[b] = (float)sqrt(fmax(e, 0.0) / dn + 1e-7);
}

extern "C" void kernel_launch(void* const* d_in, const int* in_sizes, int n_in,
                              void* d_out, int out_size, void* d_ws, size_t ws_size,
                              hipStream_t stream) {
    const float* inp = (const float*)d_in[0];
    const float* tgt = (const float*)d_in[1];
    const int* natoms = (const int*)d_in[2];
    float* out = (float*)d_out;
    float* ws = (float*)d_ws;
    (void)ws_size; (void)n_in; (void)in_sizes;
    kabsch_reduce_kernel<<<dim3(out_size), dim3(192), 0, stream>>>(inp, tgt, natoms, ws);
    kabsch_finish_kernel<<<dim3(out_size / 256), dim3(256), 0, stream>>>(ws, natoms, out);
}